// Round 11
// baseline (371.237 us; speedup 1.0000x reference)
//
#include <hip/hip_runtime.h>
#include <hip/hip_bf16.h>

using bf16 = __hip_bfloat16;
typedef __attribute__((ext_vector_type(4))) float f32x4;
typedef __attribute__((ext_vector_type(8))) short bf16x8;

#define NPX 4096
#define CCH 512

struct Ptr8 { void* p[8]; };

struct GemmP {
  const bf16* A; const bf16* B; void* C;
  const float* bias_m; const float* bias_n; const float* resid;
  float* rspart;
  float alpha; int K;
  int lda, ldb, ldc;
  long long sA, sB, sC, sR;
  int gx, gy;
  int omode;
};

__device__ __forceinline__ void async16(const bf16* g, bf16* l) {
  __builtin_amdgcn_global_load_lds((const __attribute__((address_space(1))) void*)g,
                                   (__attribute__((address_space(3))) void*)l, 16, 0, 0);
}

__device__ __forceinline__ float bfb2f(short s) {
  unsigned u = ((unsigned)(unsigned short)s) << 16;
  float f;
  __builtin_memcpy(&f, &u, 4);
  return f;
}

__device__ __forceinline__ short f2bfb(float f) {
  bf16 h = __float2bfloat16(f);
  short s;
  __builtin_memcpy(&s, &h, 2);
  return s;
}

// ---------------- prep: weight convert + bias pack + GN partial sums ----------
__global__ __launch_bounds__(256) void prep_kernel(
    const float* __restrict__ wq, const float* __restrict__ wk,
    const float* __restrict__ wv, const float* __restrict__ wp,
    const float* __restrict__ bq, const float* __restrict__ bk,
    const float* __restrict__ x,
    bf16* __restrict__ wout, float* __restrict__ bqk, float* __restrict__ pstats) {
  int bid = blockIdx.x;
  int t = threadIdx.x;
  if (bid < 1024) {
    int tid = bid * 256 + t;
    int i = tid * 4;
    int seg = i >> 18;
    const float* in = seg == 0 ? wq : seg == 1 ? wk : seg == 2 ? wv : wp;
    float4 v = *reinterpret_cast<const float4*>(in + (i & 262143));
    wout[i]     = __float2bfloat16(v.x);
    wout[i + 1] = __float2bfloat16(v.y);
    wout[i + 2] = __float2bfloat16(v.z);
    wout[i + 3] = __float2bfloat16(v.w);
    if (tid < 256) {
      int j = tid * 4;
      const float* bsrc = j < 512 ? bq : bk;
      float4 b = *reinterpret_cast<const float4*>(bsrc + (j & 511));
      *reinterpret_cast<float4*>(bqk + j) = b;
    }
  } else {
    int bp = bid - 1024;
    const float* p = x + (size_t)bp * 8192;
    float s = 0.f, s2 = 0.f;
    #pragma unroll
    for (int j = 0; j < 8; j++) {
      float4 v = *reinterpret_cast<const float4*>(p + j * 1024 + t * 4);
      s  += v.x + v.y + v.z + v.w;
      s2 += v.x * v.x + v.y * v.y + v.z * v.z + v.w * v.w;
    }
    #pragma unroll
    for (int off = 32; off >= 1; off >>= 1) {
      s  += __shfl_xor(s, off);
      s2 += __shfl_xor(s2, off);
    }
    __shared__ float ls[8];
    int wv_ = t >> 6;
    if ((t & 63) == 0) { ls[wv_ * 2] = s; ls[wv_ * 2 + 1] = s2; }
    __syncthreads();
    if (t == 0) {
      pstats[bp * 2]     = ls[0] + ls[2] + ls[4] + ls[6];
      pstats[bp * 2 + 1] = ls[1] + ls[3] + ls[5] + ls[7];
    }
  }
}

// ---------------- GroupNorm apply + transpose to [n][c] bf16 -------------------
__global__ __launch_bounds__(256) void gn_apply_kernel(const float* __restrict__ x,
    const float* __restrict__ pstats, const float* __restrict__ gamma,
    const float* __restrict__ beta, bf16* __restrict__ h) {
  __shared__ float tile[64][65];
  __shared__ float mr[4][2];
  int b  = blockIdx.z;
  int c0 = blockIdx.x * 64, n0 = blockIdx.y * 64;
  int t  = threadIdx.x;
  if (t < 4) {
    int g = (c0 >> 4) + t;
    float S = 0.f, S2 = 0.f;
    #pragma unroll
    for (int k2 = 0; k2 < 8; k2++) {
      S  += pstats[((b * 32 + g) * 8 + k2) * 2];
      S2 += pstats[((b * 32 + g) * 8 + k2) * 2 + 1];
    }
    float mean = S * (1.f / 65536.f);
    float var  = S2 * (1.f / 65536.f) - mean * mean;
    mr[t][0] = mean;
    mr[t][1] = rsqrtf(var + 1e-6f);
  }
  __syncthreads();
  int cl = t >> 6, nl = t & 63;
  #pragma unroll
  for (int i = 0; i < 16; i++) {
    int c = c0 + cl + i * 4;
    float v = x[((size_t)b * CCH + c) * NPX + n0 + nl];
    int gi = (cl + i * 4) >> 4;
    tile[cl + i * 4][nl] = (v - mr[gi][0]) * mr[gi][1] * gamma[c] + beta[c];
  }
  __syncthreads();
  #pragma unroll
  for (int i = 0; i < 16; i++) {
    int n = cl + i * 4;
    int c = nl;
    h[((size_t)b * NPX + n0 + n) * CCH + c0 + c] = __float2bfloat16(tile[c][n]);
  }
}

// ---------------- generic B^T GEMM, 1-D grid, dual param blocks ----------------
__global__ __launch_bounds__(256, 4) void gemm_any_kernel(GemmP p0, GemmP p1, unsigned nb0) {
  unsigned nwg = gridDim.x;
  unsigned flat = blockIdx.x;
  unsigned swz = (flat & 7) * (nwg >> 3) + (flat >> 3);
  GemmP p = swz < nb0 ? p0 : p1;
  unsigned local = swz < nb0 ? swz : swz - nb0;
  unsigned bxi = local % p.gx;
  unsigned tmp = local / p.gx;
  unsigned byi = tmp % p.gy;
  unsigned bz  = tmp / p.gy;

  const bf16* A = p.A + (size_t)bz * p.sA;
  const bf16* B = p.B + (size_t)bz * p.sB;
  const int m0 = bxi * 128, n0 = byi * 128;

  __shared__ bf16 ldsA[128 * 64];
  __shared__ bf16 ldsB[128 * 64];

  const int t = threadIdx.x;
  const int lane = t & 63, wv = t >> 6;
  const int wr = (wv >> 1) * 64, wc = (wv & 1) * 64;

  const int r0 = t >> 3;
  const int cb = ((t & 7) << 4) ^ ((r0 & 7) << 4);
  const bf16* gA = A + (size_t)(m0 + r0) * p.lda + (cb >> 1);
  const bf16* gB = B + (size_t)(n0 + r0) * p.ldb + (cb >> 1);
  bf16* lA = ldsA + t * 8;
  bf16* lB = ldsB + t * 8;

  const int arow = wr + (lane & 15);
  const int brow = wc + (lane & 15);
  const int kb   = (lane >> 4) * 16;

  f32x4 acc[4][4] = {};

  for (int k0 = 0; k0 < p.K; k0 += 64) {
    #pragma unroll
    for (int i = 0; i < 4; i++) {
      async16(gA + (size_t)i * 32 * p.lda + k0, lA + i * 2048);
      async16(gB + (size_t)i * 32 * p.ldb + k0, lB + i * 2048);
    }
    __syncthreads();
    #pragma unroll
    for (int ks = 0; ks < 2; ks++) {
      bf16x8 af[4], bfr[4];
      #pragma unroll
      for (int f = 0; f < 4; f++) {
        int ra = arow + f * 16;
        af[f] = *reinterpret_cast<const bf16x8*>(
            reinterpret_cast<const char*>(ldsA) + ra * 128 + ((ks * 64 + kb) ^ ((ra & 7) << 4)));
        int rb = brow + f * 16;
        bfr[f] = *reinterpret_cast<const bf16x8*>(
            reinterpret_cast<const char*>(ldsB) + rb * 128 + ((ks * 64 + kb) ^ ((rb & 7) << 4)));
      }
      #pragma unroll
      for (int fm = 0; fm < 4; fm++)
        #pragma unroll
        for (int fn = 0; fn < 4; fn++)
          acc[fm][fn] = __builtin_amdgcn_mfma_f32_16x16x32_bf16(af[fm], bfr[fn], acc[fm][fn], 0, 0, 0);
    }
    __syncthreads();
  }

  #pragma unroll
  for (int fm = 0; fm < 4; fm++) {
    #pragma unroll
    for (int j = 0; j < 4; j++) {
      int gm = m0 + wr + fm * 16 + (lane >> 4) * 4 + j;
      if (p.omode == 2) {
        float rsum = 0.f;
        #pragma unroll
        for (int fn = 0; fn < 4; fn++) {
          int gn = n0 + wc + fn * 16 + (lane & 15);
          float e = __expf(acc[fm][fn][j] * p.alpha);
          rsum += e;
          reinterpret_cast<bf16*>(p.C)[(size_t)bz * p.sC + (size_t)gm * p.ldc + gn] = __float2bfloat16(e);
        }
        rsum += __shfl_xor(rsum, 1);
        rsum += __shfl_xor(rsum, 2);
        rsum += __shfl_xor(rsum, 4);
        rsum += __shfl_xor(rsum, 8);
        if ((lane & 15) == 0)
          p.rspart[(((size_t)bz * 4096 + gm) << 6) + byi * 2 + (wv & 1)] = rsum;
      } else {
        float bm = p.bias_m ? p.bias_m[gm] : 0.f;
        #pragma unroll
        for (int fn = 0; fn < 4; fn++) {
          int gn = n0 + wc + fn * 16 + (lane & 15);
          float vv = acc[fm][fn][j] * p.alpha + bm;
          if (p.bias_n) vv += p.bias_n[gn];
          if (p.resid)  vv += p.resid[(size_t)bz * p.sR + (size_t)gm * p.ldc + gn];
        if (p.omode == 1)
            reinterpret_cast<bf16*>(p.C)[(size_t)bz * p.sC + (size_t)gm * p.ldc + gn] = __float2bfloat16(vv);
          else
            reinterpret_cast<float*>(p.C)[(size_t)bz * p.sC + (size_t)gm * p.ldc + gn] = vv;
        }
      }
    }
  }
}

// =================== shared 8-phase 256x256 machinery ==========================
#define BAR() __builtin_amdgcn_s_barrier()
#define LGKM0() do { asm volatile("s_waitcnt lgkmcnt(0)" ::: "memory"); \
                     __builtin_amdgcn_sched_barrier(0); } while (0)
#define VMC2() do { asm volatile("s_waitcnt vmcnt(2)" ::: "memory"); \
                    __builtin_amdgcn_sched_barrier(0); } while (0)
#define VMC0() do { asm volatile("s_waitcnt vmcnt(0)" ::: "memory"); \
                    __builtin_amdgcn_sched_barrier(0); } while (0)

#define STG(op, buf, half, kt, LD) do { \
    const bf16* _s = (op ? gB : gA) + (size_t)((half) * 128) * (LD) + (kt) * 64; \
    bf16* _d = &lds[op][buf][half][t * 8]; \
    async16(_s, _d); \
    async16(_s + (size_t)64 * (LD), _d + 4096); \
  } while (0)

// qk variant: source base selected by kt (tile1 = batch0, tile2 = batch1), ld=1024
#define STGQ(op, buf, half, kt) do { \
    int _k = (kt); \
    const bf16* _base = (op) ? (_k < 8 ? gB0 : gB1) : (_k < 8 ? gA0 : gA1); \
    const bf16* _s = _base + (size_t)((half) * 128) * 1024 + (_k & 7) * 64; \
    bf16* _d = &lds[op][buf][half][t * 8]; \
    async16(_s, _d); \
    async16(_s + (size_t)64 * 1024, _d + 4096); \
  } while (0)

#define DSA(buf, mrb) do { \
    _Pragma("unroll") \
    for (int mi = 0; mi < 4; mi++) { \
      int _r = ((mrb) + mi) * 16 + (l & 15); \
      _Pragma("unroll") \
      for (int ks = 0; ks < 2; ks++) \
        aR[mi][ks] = *reinterpret_cast<const bf16x8*>( \
            &lds[0][buf][wm][_r * 64 + ((ks * 32 + (l >> 4) * 8) ^ ((l & 7) << 3))]); \
    } } while (0)

#define DSB(buf, nrb) do { \
    _Pragma("unroll") \
    for (int ni = 0; ni < 2; ni++) { \
      int _r = (wn & 1) * 64 + ((nrb) + ni) * 16 + (l & 15); \
      _Pragma("unroll") \
      for (int ks = 0; ks < 2; ks++) \
        bR[ni][ks] = *reinterpret_cast<const bf16x8*>( \
            &lds[1][buf][wn >> 1][_r * 64 + ((ks * 32 + (l >> 4) * 8) ^ ((l & 7) << 3))]); \
    } } while (0)

#define MMAQ(qm, qn) do { \
    _Pragma("unroll") \
    for (int mi = 0; mi < 4; mi++) \
    _Pragma("unroll") \
    for (int ni = 0; ni < 2; ni++) \
    _Pragma("unroll") \
    for (int ks = 0; ks < 2; ks++) \
      acc[(qm) * 4 + mi][(qn) * 2 + ni] = __builtin_amdgcn_mfma_f32_16x16x32_bf16( \
          aR[mi][ks], bR[ni][ks], acc[(qm) * 4 + mi][(qn) * 2 + ni], 0, 0, 0); \
  } while (0)

#define PH_TAIL(qm, qn) do { \
    BAR(); LGKM0(); \
    __builtin_amdgcn_s_setprio(1); MMAQ(qm, qn); __builtin_amdgcn_s_setprio(0); \
    BAR(); } while (0)

// =================== 8-phase PV kernel (split-K=4) =============================
__global__ __launch_bounds__(512, 1) void pv8_kernel(
    const bf16* __restrict__ Sb, const bf16* __restrict__ vb,
    const float* __restrict__ rspart, Ptr8 slots) {
  unsigned nwg = gridDim.x;   // 256
  unsigned flat = blockIdx.x;
  unsigned swz = (flat & 7) * (nwg >> 3) + (flat >> 3);
  const unsigned zz = swz >> 5;
  const unsigned tile = swz & 31;
  const int m0 = (tile & 15) * 256;
  const int n0 = (tile >> 4) * 256;
  const int b = zz >> 2, s = zz & 3;
  const bf16* A = Sb + (size_t)b * 16777216 + s * 1024;
  const bf16* B = vb + (size_t)b * 2097152 + s * 1024;
  bf16* Cp = (bf16*)(slots.p[zz]);

  __shared__ bf16 lds[2][2][2][8192];
  __shared__ float rs_lds[256];

  const int t = threadIdx.x;
  const int l = t & 63;
  const int wid = t >> 6;
  const int wm = wid >> 2;
  const int wn = wid & 3;

  const int swzc = (((t & 7) ^ ((t >> 3) & 7)) << 3);
  const bf16* gA = A + (size_t)(m0 + (t >> 3)) * 4096 + swzc;
  const bf16* gB = B + (size_t)(n0 + (t >> 3)) * 4096 + swzc;

  f32x4 acc[8][4] = {};
  bf16x8 aR[4][2], bR[2][2];

  STG(0, 0, 0, 0, 4096);
  STG(0, 0, 1, 0, 4096);
  STG(1, 0, 0, 0, 4096);
  STG(1, 0, 1, 0, 4096);
  STG(1, 1, 0, 1, 4096);
  VMC0();
  BAR();

  #pragma unroll 1
  for (int j = 0; j < 7; j++) {
    const int kt1 = 2 * j + 1, kt2 = 2 * j + 2, kt3 = 2 * j + 3;
    DSA(0, 0); DSB(0, 0); STG(1, 1, 1, kt1, 4096); PH_TAIL(0, 0);
    DSA(0, 4);            STG(0, 1, 0, kt1, 4096); PH_TAIL(1, 0);
    DSB(0, 2);            STG(0, 1, 1, kt1, 4096); PH_TAIL(1, 1);
    DSA(0, 0);            STG(1, 0, 0, kt2, 4096); VMC2(); PH_TAIL(0, 1);
    DSA(1, 0); DSB(1, 0); STG(1, 0, 1, kt2, 4096); PH_TAIL(0, 0);
    DSA(1, 4);            STG(0, 0, 0, kt2, 4096); PH_TAIL(1, 0);
    DSB(1, 2);            STG(0, 0, 1, kt2, 4096); PH_TAIL(1, 1);
    DSA(1, 0);            STG(1, 1, 0, kt3, 4096); VMC2(); PH_TAIL(0, 1);
  }
  {
    const int kt1 = 15;
    DSA(0, 0); DSB(0, 0); STG(1, 1, 1, kt1, 4096); PH_TAIL(0, 0);
    DSA(0, 4);            STG(0, 1, 0, kt1, 4096); PH_TAIL(1, 0);
    DSB(0, 2);            STG(0, 1, 1, kt1, 4096); PH_TAIL(1, 1);
    DSA(0, 0);            VMC0(); PH_TAIL(0, 1);
    DSA(1, 0); DSB(1, 0); PH_TAIL(0, 0);
    DSA(1, 4);            PH_TAIL(1, 0);
    DSB(1, 2);            PH_TAIL(1, 1);
    DSA(1, 0);            PH_TAIL(0, 1);
  }

  if (t < 256) {
    const float4* pp = reinterpret_cast<const float4*>(
        rspart + (((size_t)b * 4096 + m0 + t) << 6));
    float ssum = 0.f;
    #pragma unroll
    for (int i2 = 0; i2 < 16; i2++) {
      float4 vv = pp[i2];
      ssum += vv.x + vv.y + vv.z + vv.w;
    }
    rs_lds[t] = 1.0f / ssum;
  }
  __syncthreads();

  #pragma unroll
  for (int mr = 0; mr < 8; mr++) {
    #pragma unroll
    for (int jj = 0; jj < 4; jj++) {
      int lrow = wm * 128 + mr * 16 + (l >> 4) * 4 + jj;
      float inv = rs_lds[lrow];
      int gm = m0 + lrow;
      #pragma unroll
      for (int nr = 0; nr < 4; nr++) {
        int gn = n0 + wn * 64 + nr * 16 + (l & 15);
        Cp[(size_t)gm * 512 + gn] = __float2bfloat16(acc[mr][nr][jj] * inv);
      }
    }
  }
}

// =================== 8-phase QK^T kernel, batch-merged (16-kt pipeline) ========
// 256 blocks; each block computes the same 256x256 tile for batch 0 (kt 0..7)
// then batch 1 (kt 8..15) in one continuous pipeline; mid-epilogue after kt 7.
__global__ __launch_bounds__(512, 1) void qk8_kernel(
    const bf16* __restrict__ qkb, bf16* __restrict__ Sb,
    float* __restrict__ rspart, float scale) {
  unsigned nwg = gridDim.x;   // 256
  unsigned flat = blockIdx.x;
  unsigned swz = (flat & 7) * (nwg >> 3) + (flat >> 3);
  const unsigned tile = swz & 255;       // 16 m-tiles x 16 n-tiles
  const int m0 = (tile & 15) * 256;
  const int n0 = (tile >> 4) * 256;

  __shared__ bf16 lds[2][2][2][8192];

  const int t = threadIdx.x;
  const int l = t & 63;
  const int wid = t >> 6;
  const int wm = wid >> 2;
  const int wn = wid & 3;

  const int swzc = (((t & 7) ^ ((t >> 3) & 7)) << 3);
  const bf16* gA0 = qkb + (size_t)(m0 + (t >> 3)) * 1024 + swzc;         // q, b0
  const bf16* gB0 = qkb + 512 + (size_t)(n0 + (t >> 3)) * 1024 + swzc;   // k, b0
  const bf16* gA1 = gA0 + 4194304;                                       // b1
  const bf16* gB1 = gB0 + 4194304;

  f32x4 acc[8][4] = {};
  bf16x8 aR[4][2], bR[2][2];

  auto epi = [&](int b) {
    const int ntile = tile >> 4;
    bf16* Cp = Sb + (size_t)b * 16777216;
    #pragma unroll
    for (int mr = 0; mr < 8; mr++) {
      #pragma unroll
      for (int jj = 0; jj < 4; jj++) {
        int gm = m0 + wm * 128 + mr * 16 + (l >> 4) * 4 + jj;
        float rsum = 0.f;
        #pragma unroll
        for (int nr = 0; nr < 4; nr++) {
          int gn = n0 + wn * 64 + nr * 16 + (l & 15);
          float e = __expf(acc[mr][nr][jj] * scale);
          rsum += e;
          Cp[(size_t)gm * 4096 + gn] = __float2bfloat16(e);
        }
        rsum += __shfl_xor(rsum, 1);
        rsum += __shfl_xor(rsum, 2);
        rsum += __shfl_xor(rsum, 4);
        rsum += __shfl_xor(rsum, 8);
        if ((l & 15) == 0)
          rspart[(((size_t)b * 4096 + gm) << 6) + ntile * 4 + wn] = rsum;
      }
    }
  };

  // kt 0..7 = batch0 (K=512), kt 8..15 = batch1. Same schedule as pv8.
  STGQ(0, 0, 0, 0);
  STGQ(0, 0, 1, 0);
  STGQ(1, 0, 0, 0);
  STGQ(1, 0, 1, 0);
  STGQ(1, 1, 0, 1);
  VMC0();
  BAR();

  #pragma unroll 1
  for (int j = 0; j < 7; j++) {
    const int kt1 = 2 * j + 1, kt2 = 2 * j + 2, kt3 = 2 * j + 3;
    DSA(0, 0); DSB(0, 0); STGQ(1, 1, 1, kt1); PH_TAIL(0, 0);
    DSA(0, 4);            STGQ(0, 1, 0, kt1); PH_TAIL(1, 0);
    DSB(0, 2);            STGQ(0, 1, 1, kt1); PH_TAIL(1, 1);
    DSA(0, 0);            STGQ(1, 0, 0, kt2); VMC2(); PH_TAIL(0, 1);
    DSA(1, 0); DSB(1, 0); STGQ(1, 0, 1, kt2); PH_TAIL(0, 0);
    DSA(1, 4);            STGQ(0, 0, 0, kt2); PH_TAIL(1, 0);
    DSB(1, 2);            STGQ(0, 0, 1, kt2); PH_TAIL(1, 1);
    DSA(1, 0);            STGQ(1, 1, 0, kt3); VMC2(); PH_TAIL(0, 1);
    if (j == 3) {
      // batch0 tile complete (kt 0..7): write its epilogue, reset acc
      epi(0);
      #pragma unroll
      for (int a1 = 0; a1 < 8; a1++)
        #pragma unroll
        for (int a2 = 0; a2 < 4; a2++)
          acc[a1][a2] = f32x4{0.f, 0.f, 0.f, 0.f};
    }
  }
  {
    const int kt1 = 15;
    DSA(0, 0); DSB(0, 0); STGQ(1, 1, 1, kt1); PH_TAIL(0, 0);
    DSA(0, 4);            STGQ(0, 1, 0, kt1); PH_TAIL(1, 0);
    DSB(0, 2);            STGQ(0, 1, 1, kt1); PH_TAIL(1, 1);
    DSA(0, 0);            VMC0(); PH_TAIL(0, 1);
    DSA(1, 0); DSB(1, 0); PH_TAIL(0, 0);
    DSA(1, 4);            PH_TAIL(1, 0);
    DSB(1, 2);            PH_TAIL(1, 1);
    DSA(1, 0);            PH_TAIL(0, 1);
  }
  epi(1);
}

// ---------------- PV split-K fallback (small-ws path), 128^2 structure ---------
__global__ __launch_bounds__(256, 4) void pv_split_kernel(
    const bf16* __restrict__ Sb, const bf16* __restrict__ vb,
    const float* __restrict__ rspart,
    long long sS, long long sV, Ptr8 slots, int mode) {
  unsigned nx = gridDim.x, ny = gridDim.y;
  unsigned flat = (blockIdx.z * ny + blockIdx.y) * nx + blockIdx.x;
  unsigned nwg = nx * ny * gridDim.z;
  unsigned swz = (flat & 7) * (nwg >> 3) + (flat >> 3);
  unsigned bxi = swz % nx;
  unsigned tmp = swz / nx;
  unsigned byi = tmp % ny;
  unsigned bz  = tmp / ny;

  const int z = bz;
  const int b = mode ? 0 : (z >> 2);
  const int s = mode ? z : (z & 3);
  const bf16* A = Sb + (size_t)b * sS + s * 1024;
  const bf16* B = vb + (size_t)b * sV + s * 1024;
  bf16* Cp = (bf16*)(slots.p[z]);
  const int m0 = bxi * 128, n0 = byi * 128;

  __shared__ bf16 ldsA[128 * 64];
  __shared__ bf16 ldsB[128 * 64];
  __shared__ float rs_lds[128];

  const int t = threadIdx.x;

  if (t < 128) {
    const float4* pp = reinterpret_cast<const float4*>(rspart + (((size_t)b * 4096 + m0 + t) << 6));
    float ssum = 0.f;
    #pragma unroll
    for (int i2 = 0; i2 < 16; i2++) {
      float4 vv = pp[i2];
      ssum += vv.x + vv.y + vv.z + vv.w;
    }
    rs_lds[t] = 1.0f / ssum;
  }

  const int lane = t & 63, wv = t >> 6;
  const int wr = (wv >> 1) * 64, wc = (wv & 1) * 64;

  const int r0 = t >> 3;
  const int cb = ((t & 7) << 4) ^ ((r0 & 7) << 4);
  const bf16* gA = A + (size_t)(m0 + r0) * 4096 + (cb >> 1);
  const bf16* gB = B + (size_t)(n0 + r0) * 4096 + (cb >> 1);
  bf16* lA = ldsA + t * 8;
  bf16* lB = ldsB + t * 8;

  const int arow = wr + (lane & 15);
  const int brow = wc + (lane & 15);
  const int kb   = (lane >> 4) * 16;

  f32x4 acc[4][4] = {};

  for (int k0 = 0; k0 < 1024; k0 += 64) {
    #pragma unroll
    for (int i = 0; i < 4; i++) {
      async16(gA + (size_t)i * 32 * 4096 + k0, lA + i * 2048);
      async16(gB + (size_t)i * 32 * 4096 + k0, lB + i * 2048);
    }
    __syncthreads();
    #pragma unroll
    for (int ks = 0; ks < 2; ks++) {
      bf16x8 af[4], bfr[4];
      #pragma unroll
      for (int f = 0; f < 4; f++) {
        int ra = arow + f * 16;
        af[f] = *reinterpret_cast<const bf16x8*>(
            reinterpret_cast<const char*>(ldsA) + ra * 128 + ((ks * 64 + kb) ^ ((ra & 7) << 4)));
        int rb = brow + f * 16;
        bfr[f] = *reinterpret_cast<const bf16x8*>(
            reinterpret_cast<const char*>(ldsB) + rb * 128 + ((ks * 64 + kb) ^ ((rb & 7) << 4)));
      }
      #pragma unroll
      for (int fm = 0; fm < 4; fm++)
        #pragma unroll
        for (int fn = 0; fn < 4; fn++)
          acc[fm][fn] = __builtin_amdgcn_mfma_f32_16x16x32_bf16(af[fm], bfr[fn], acc[fm][fn], 0, 0, 0);
    }
    __syncthreads();
  }

  #pragma unroll
  for (int fm = 0; fm < 4; fm++) {
    #pragma unroll
    for (int j = 0; j < 4; j++) {
      int lrow = wr + fm * 16 + (lane >> 4) * 4 + j;
      float inv = rs_lds[lrow];
      int gm = m0 + lrow;
      #pragma unroll
      for (int fn = 0; fn < 4; fn++) {
        int gn = n0 + wc + fn * 16 + (lane & 15);
        Cp[(size_t)gm * 512 + gn] = __float2bfloat16(acc[fm][fn][j] * inv);
      }
    }
  }
}

// ---------------- merged split-K reduce (both batches, one launch) -------------
__global__ __launch_bounds__(256) void reduce3x2_kernel(bf16* __restrict__ o,
    const bf16* __restrict__ h, const bf16* __restrict__ qk) {
  int i = (blockIdx.x * 256 + threadIdx.x) * 8;
  int b = i >> 21;
  int ii = i & 2097151;
  bf16* dst = o + (size_t)b * 2097152 + ii;
  const bf16* p1 = h + (size_t)b * 2097152 + ii;
  const bf16* p2 = qk + (size_t)b * 2 * 2097152 + ii;
  const bf16* p3 = qk + (size_t)(b * 2 + 1) * 2097152 + ii;
  bf16x8 a  = *reinterpret_cast<const bf16x8*>(dst);
  bf16x8 v1 = *reinterpret_cast<const bf16x8*>(p1);
  bf16x8 v2 = *reinterpret_cast<const bf16x8*>(p2);
  bf16x8 v3 = *reinterpret_cast<const bf16x8*>(p3);
  bf16x8 r;
  #pragma unroll
  for (int j = 0; j < 8; j++)
    r[j] = f2bfb(bfb2f(a[j]) + bfb2f(v1[j]) + bfb2f(v2[j]) + bfb2f(v3[j]));
  *reinterpret_cast<bf16x8*>(dst) = r;
}

// ---------------- fallback reduce --------------------------------------------
__global__ __launch_bounds__(256) void reduce3_kernel(bf16* __restrict__ dst,
    const bf16* __restrict__ p1, const bf16* __restrict__ p2,
    const bf16* __restrict__ p3) {
  int i = (blockIdx.x * 256 + threadIdx.x) * 8;
  bf16x8 a  = *reinterpret_cast<const bf16x8*>(dst + i);
  bf16x8 v1 = *reinterpret_cast<const bf16x8*>(p1 + i);
  bf16x8 v2 = *reinterpret_cast<const bf16x8*>(p2 + i);
  bf16x8 v3 = *reinterpret_cast<const bf16x8*>(p3 + i);
  bf16x8 r;
  #pragma unroll
  for (int j = 0; j < 8; j++)
    r[j] = f2bfb(bfb2f(a[j]) + bfb2f(v1[j]) + bfb2f(v2[j]) + bfb2f(v3[j]));
  *reinterpret_cast<bf16x8*>(dst + i) = r;
}

extern "C" void kernel_launch(void* const* d_in, const int* in_sizes, int n_in,
                              void* d_out, int out_size, void* d_ws, size_t ws_size,
                              hipStream_t stream) {
  const float* x     = (const float*)d_in[0];
  const float* gamma = (const float*)d_in[1];
  const float* beta  = (const float*)d_in[2];
  const float* wq    = (const float*)d_in[3];
  const float* bq    = (const float*)d_in[4];
  const float* wk    = (const float*)d_in[5];
  const float* bk    = (const float*)d_in[6];
  const float* wv    = (const float*)d_in[7];
  const float* bv    = (const float*)d_in[8];
  const float* wp    = (const float*)d_in[9];
  const float* bp    = (const float*)d_in[10];
  float* out = (float*)d_out;

  char* w = (char*)d_ws;
  size_t off = 0;
  float* pstats = (float*)(w + off);   off += 4096;
  float* bqk    = (float*)(w + off);   off += 4096;
  float* rspart = (float*)(w + off);   off += (size_t)2 * 4096 * 64 * 4;
  bf16* wqkb = (bf16*)(w + off);       off += (size_t)1024 * 512 * 2;
  bf16* wvb  = (bf16*)(w + off);       off += (size_t)512 * 512 * 2;
  bf16* wpb  = (bf16*)(w + off);       off += (size_t)512 * 512 * 2;
  bf16* h    = (bf16*)(w + off);       off += (size_t)2 * NPX * CCH * 2;
  bf16* qk   = (bf16*)(w + off);       off += (size_t)2 * NPX * 1024 * 2;
  bf16* v    = (bf16*)(w + off);       off += (size_t)2 * NPX * CCH * 2;
  bf16* o    = (bf16*)(w + off);       off += (size_t)2 * NPX * CCH * 2;
  bf16* S    = (bf16*)(w + off);
  size_t need_big = off + (size_t)2 * NPX * NPX * 2;
  const bool big = ws_size >= need_big;

  const long long sBN = (long long)NPX * CCH;
  const long long sQK = (long long)NPX * 1024;
  const long long sS  = (long long)NPX * NPX;
  const float scale = 0.04419417382415922f;

  prep_kernel<<<1536, 256, 0, stream>>>(wq, wk, wv, wp, bq, bk, x, wqkb, bqk, pstats);
  gn_apply_kernel<<<dim3(8, 64, 2), 256, 0, stream>>>(x, pstats, gamma, beta, h);

  GemmP pqkv = {h, wqkb, qk, nullptr, bqk, nullptr, nullptr,
                1.f, 512, 512, 512, 1024, sBN, 0, sQK, 0, 32, 8, 1};
  GemmP pv   = {wvb, h, v, bv, nullptr, nullptr, nullptr,
                1.f, 512, 512, 512, 4096, 0, sBN, sBN, 0, 4, 32, 1};
  gemm_any_kernel<<<768, 256, 0, stream>>>(pqkv, pv, 512);

  if (big) {
    qk8_kernel<<<256, 512, 0, stream>>>(qk, S, rspart, scale);
    Ptr8 slots{{o, h, qk, qk + sBN, o + sBN, h + sBN, qk + 2 * sBN, qk + 3 * sBN}};
    pv8_kernel<<<256, 512, 0, stream>>>(S, v, rspart, slots);
    reduce3x2_kernel<<<2048, 256, 0, stream>>>(o, h, qk);
  } else {
    for (int b = 0; b < 2; b++) {
      GemmP ps = {qk + b * sQK, qk + b * sQK + 512, S, nullptr, nullptr, nullptr,
                  rspart + ((size_t)b << 18),
                  scale, 512, 1024, 1024, 4096, 0, 0, 0, 0, 32, 32, 2};
      gemm_any_kernel<<<1024, 256, 0, stream>>>(ps, ps, 1024);
      Ptr8 slots{{o + b * sBN, h, h + sBN, (bf16*)out, nullptr, nullptr, nullptr, nullptr}};
      pv_split_kernel<<<dim3(32, 4, 4), 256, 0, stream>>>(S, v + b * sBN,
          rspart + ((size_t)b << 18), 0, 0, slots, 1);
      reduce3_kernel<<<1024, 256, 0, stream>>>(o + b * sBN, h, h + sBN, (bf16*)out);
    }
  }

  GemmP po = {wpb, o, out, bp, nullptr, x, nullptr,
              1.f, 512, 512, 512, 4096, 0, sBN, sBN, sBN, 4, 32, 0};
  gemm_any_kernel<<<256, 256, 0, stream>>>(po, po, 256);
}

// Round 12
// 243.667 us; speedup vs baseline: 1.5235x; 1.5235x over previous
//
#include <hip/hip_runtime.h>
#include <hip/hip_bf16.h>

using bf16 = __hip_bfloat16;
typedef __attribute__((ext_vector_type(4))) float f32x4;
typedef __attribute__((ext_vector_type(8))) short bf16x8;

#define NPX 4096
#define CCH 512

struct Ptr8 { void* p[8]; };

struct GemmP {
  const bf16* A; const bf16* B; void* C;
  const float* bias_m; const float* bias_n; const float* resid;
  float* rspart;
  float alpha; int K;
  int lda, ldb, ldc;
  long long sA, sB, sC, sR;
  int gx, gy;
  int omode;
};

__device__ __forceinline__ void async16(const bf16* g, bf16* l) {
  __builtin_amdgcn_global_load_lds((const __attribute__((address_space(1))) void*)g,
                                   (__attribute__((address_space(3))) void*)l, 16, 0, 0);
}

__device__ __forceinline__ float bfb2f(short s) {
  unsigned u = ((unsigned)(unsigned short)s) << 16;
  float f;
  __builtin_memcpy(&f, &u, 4);
  return f;
}

__device__ __forceinline__ short f2bfb(float f) {
  bf16 h = __float2bfloat16(f);
  short s;
  __builtin_memcpy(&s, &h, 2);
  return s;
}

// ---------------- prep: weight convert + bias pack + GN partial sums ----------
__global__ __launch_bounds__(256) void prep_kernel(
    const float* __restrict__ wq, const float* __restrict__ wk,
    const float* __restrict__ wv, const float* __restrict__ wp,
    const float* __restrict__ bq, const float* __restrict__ bk,
    const float* __restrict__ x,
    bf16* __restrict__ wout, float* __restrict__ bqk, float* __restrict__ pstats) {
  int bid = blockIdx.x;
  int t = threadIdx.x;
  if (bid < 1024) {
    int tid = bid * 256 + t;
    int i = tid * 4;
    int seg = i >> 18;
    const float* in = seg == 0 ? wq : seg == 1 ? wk : seg == 2 ? wv : wp;
    float4 v = *reinterpret_cast<const float4*>(in + (i & 262143));
    wout[i]     = __float2bfloat16(v.x);
    wout[i + 1] = __float2bfloat16(v.y);
    wout[i + 2] = __float2bfloat16(v.z);
    wout[i + 3] = __float2bfloat16(v.w);
    if (tid < 256) {
      int j = tid * 4;
      const float* bsrc = j < 512 ? bq : bk;
      float4 b = *reinterpret_cast<const float4*>(bsrc + (j & 511));
      *reinterpret_cast<float4*>(bqk + j) = b;
    }
  } else {
    int bp = bid - 1024;
    const float* p = x + (size_t)bp * 8192;
    float s = 0.f, s2 = 0.f;
    #pragma unroll
    for (int j = 0; j < 8; j++) {
      float4 v = *reinterpret_cast<const float4*>(p + j * 1024 + t * 4);
      s  += v.x + v.y + v.z + v.w;
      s2 += v.x * v.x + v.y * v.y + v.z * v.z + v.w * v.w;
    }
    #pragma unroll
    for (int off = 32; off >= 1; off >>= 1) {
      s  += __shfl_xor(s, off);
      s2 += __shfl_xor(s2, off);
    }
    __shared__ float ls[8];
    int wv_ = t >> 6;
    if ((t & 63) == 0) { ls[wv_ * 2] = s; ls[wv_ * 2 + 1] = s2; }
    __syncthreads();
    if (t == 0) {
      pstats[bp * 2]     = ls[0] + ls[2] + ls[4] + ls[6];
      pstats[bp * 2 + 1] = ls[1] + ls[3] + ls[5] + ls[7];
    }
  }
}

// ---------------- GroupNorm apply + transpose to [n][c] bf16 -------------------
__global__ __launch_bounds__(256) void gn_apply_kernel(const float* __restrict__ x,
    const float* __restrict__ pstats, const float* __restrict__ gamma,
    const float* __restrict__ beta, bf16* __restrict__ h) {
  __shared__ float tile[64][65];
  __shared__ float mr[4][2];
  int b  = blockIdx.z;
  int c0 = blockIdx.x * 64, n0 = blockIdx.y * 64;
  int t  = threadIdx.x;
  if (t < 4) {
    int g = (c0 >> 4) + t;
    float S = 0.f, S2 = 0.f;
    #pragma unroll
    for (int k2 = 0; k2 < 8; k2++) {
      S  += pstats[((b * 32 + g) * 8 + k2) * 2];
      S2 += pstats[((b * 32 + g) * 8 + k2) * 2 + 1];
    }
    float mean = S * (1.f / 65536.f);
    float var  = S2 * (1.f / 65536.f) - mean * mean;
    mr[t][0] = mean;
    mr[t][1] = rsqrtf(var + 1e-6f);
  }
  __syncthreads();
  int cl = t >> 6, nl = t & 63;
  #pragma unroll
  for (int i = 0; i < 16; i++) {
    int c = c0 + cl + i * 4;
    float v = x[((size_t)b * CCH + c) * NPX + n0 + nl];
    int gi = (cl + i * 4) >> 4;
    tile[cl + i * 4][nl] = (v - mr[gi][0]) * mr[gi][1] * gamma[c] + beta[c];
  }
  __syncthreads();
  #pragma unroll
  for (int i = 0; i < 16; i++) {
    int n = cl + i * 4;
    int c = nl;
    h[((size_t)b * NPX + n0 + n) * CCH + c0 + c] = __float2bfloat16(tile[c][n]);
  }
}

// ---------------- generic B^T GEMM, 1-D grid, dual param blocks ----------------
__global__ __launch_bounds__(256, 4) void gemm_any_kernel(GemmP p0, GemmP p1, unsigned nb0) {
  unsigned nwg = gridDim.x;
  unsigned flat = blockIdx.x;
  unsigned swz = (flat & 7) * (nwg >> 3) + (flat >> 3);
  GemmP p = swz < nb0 ? p0 : p1;
  unsigned local = swz < nb0 ? swz : swz - nb0;
  unsigned bxi = local % p.gx;
  unsigned tmp = local / p.gx;
  unsigned byi = tmp % p.gy;
  unsigned bz  = tmp / p.gy;

  const bf16* A = p.A + (size_t)bz * p.sA;
  const bf16* B = p.B + (size_t)bz * p.sB;
  const int m0 = bxi * 128, n0 = byi * 128;

  __shared__ bf16 ldsA[128 * 64];
  __shared__ bf16 ldsB[128 * 64];

  const int t = threadIdx.x;
  const int lane = t & 63, wv = t >> 6;
  const int wr = (wv >> 1) * 64, wc = (wv & 1) * 64;

  const int r0 = t >> 3;
  const int cb = ((t & 7) << 4) ^ ((r0 & 7) << 4);
  const bf16* gA = A + (size_t)(m0 + r0) * p.lda + (cb >> 1);
  const bf16* gB = B + (size_t)(n0 + r0) * p.ldb + (cb >> 1);
  bf16* lA = ldsA + t * 8;
  bf16* lB = ldsB + t * 8;

  const int arow = wr + (lane & 15);
  const int brow = wc + (lane & 15);
  const int kb   = (lane >> 4) * 16;

  f32x4 acc[4][4] = {};

  for (int k0 = 0; k0 < p.K; k0 += 64) {
    #pragma unroll
    for (int i = 0; i < 4; i++) {
      async16(gA + (size_t)i * 32 * p.lda + k0, lA + i * 2048);
      async16(gB + (size_t)i * 32 * p.ldb + k0, lB + i * 2048);
    }
    __syncthreads();
    #pragma unroll
    for (int ks = 0; ks < 2; ks++) {
      bf16x8 af[4], bfr[4];
      #pragma unroll
      for (int f = 0; f < 4; f++) {
        int ra = arow + f * 16;
        af[f] = *reinterpret_cast<const bf16x8*>(
            reinterpret_cast<const char*>(ldsA) + ra * 128 + ((ks * 64 + kb) ^ ((ra & 7) << 4)));
        int rb = brow + f * 16;
        bfr[f] = *reinterpret_cast<const bf16x8*>(
            reinterpret_cast<const char*>(ldsB) + rb * 128 + ((ks * 64 + kb) ^ ((rb & 7) << 4)));
      }
      #pragma unroll
      for (int fm = 0; fm < 4; fm++)
        #pragma unroll
        for (int fn = 0; fn < 4; fn++)
          acc[fm][fn] = __builtin_amdgcn_mfma_f32_16x16x32_bf16(af[fm], bfr[fn], acc[fm][fn], 0, 0, 0);
    }
    __syncthreads();
  }

  #pragma unroll
  for (int fm = 0; fm < 4; fm++) {
    #pragma unroll
    for (int j = 0; j < 4; j++) {
      int gm = m0 + wr + fm * 16 + (lane >> 4) * 4 + j;
      if (p.omode == 2) {
        float rsum = 0.f;
        #pragma unroll
        for (int fn = 0; fn < 4; fn++) {
          int gn = n0 + wc + fn * 16 + (lane & 15);
          float e = __expf(acc[fm][fn][j] * p.alpha);
          rsum += e;
          reinterpret_cast<bf16*>(p.C)[(size_t)bz * p.sC + (size_t)gm * p.ldc + gn] = __float2bfloat16(e);
        }
        rsum += __shfl_xor(rsum, 1);
        rsum += __shfl_xor(rsum, 2);
        rsum += __shfl_xor(rsum, 4);
        rsum += __shfl_xor(rsum, 8);
        if ((lane & 15) == 0)
          p.rspart[(((size_t)bz * 4096 + gm) << 6) + byi * 2 + (wv & 1)] = rsum;
      } else {
        float bm = p.bias_m ? p.bias_m[gm] : 0.f;
        #pragma unroll
        for (int fn = 0; fn < 4; fn++) {
          int gn = n0 + wc + fn * 16 + (lane & 15);
          float vv = acc[fm][fn][j] * p.alpha + bm;
          if (p.bias_n) vv += p.bias_n[gn];
          if (p.resid)  vv += p.resid[(size_t)bz * p.sR + (size_t)gm * p.ldc + gn];
          if (p.omode == 1)
            reinterpret_cast<bf16*>(p.C)[(size_t)bz * p.sC + (size_t)gm * p.ldc + gn] = __float2bfloat16(vv);
          else
            reinterpret_cast<float*>(p.C)[(size_t)bz * p.sC + (size_t)gm * p.ldc + gn] = vv;
        }
      }
    }
  }
}

// =================== shared 8-phase 256x256 machinery ==========================
#define BAR() __builtin_amdgcn_s_barrier()
#define LGKM0() do { asm volatile("s_waitcnt lgkmcnt(0)" ::: "memory"); \
                     __builtin_amdgcn_sched_barrier(0); } while (0)
#define VMC2() do { asm volatile("s_waitcnt vmcnt(2)" ::: "memory"); \
                    __builtin_amdgcn_sched_barrier(0); } while (0)
#define VMC0() do { asm volatile("s_waitcnt vmcnt(0)" ::: "memory"); \
                    __builtin_amdgcn_sched_barrier(0); } while (0)

#define STG(op, buf, half, kt, LD) do { \
    const bf16* _s = (op ? gB : gA) + (size_t)((half) * 128) * (LD) + (kt) * 64; \
    bf16* _d = &lds[op][buf][half][t * 8]; \
    async16(_s, _d); \
    async16(_s + (size_t)64 * (LD), _d + 4096); \
  } while (0)

#define DSA(buf, mrb) do { \
    _Pragma("unroll") \
    for (int mi = 0; mi < 4; mi++) { \
      int _r = ((mrb) + mi) * 16 + (l & 15); \
      _Pragma("unroll") \
      for (int ks = 0; ks < 2; ks++) \
        aR[mi][ks] = *reinterpret_cast<const bf16x8*>( \
            &lds[0][buf][wm][_r * 64 + ((ks * 32 + (l >> 4) * 8) ^ ((l & 7) << 3))]); \
    } } while (0)

#define DSB(buf, nrb) do { \
    _Pragma("unroll") \
    for (int ni = 0; ni < 2; ni++) { \
      int _r = (wn & 1) * 64 + ((nrb) + ni) * 16 + (l & 15); \
      _Pragma("unroll") \
      for (int ks = 0; ks < 2; ks++) \
        bR[ni][ks] = *reinterpret_cast<const bf16x8*>( \
            &lds[1][buf][wn >> 1][_r * 64 + ((ks * 32 + (l >> 4) * 8) ^ ((l & 7) << 3))]); \
    } } while (0)

#define MMAQ(qm, qn) do { \
    _Pragma("unroll") \
    for (int mi = 0; mi < 4; mi++) \
    _Pragma("unroll") \
    for (int ni = 0; ni < 2; ni++) \
    _Pragma("unroll") \
    for (int ks = 0; ks < 2; ks++) \
      acc[(qm) * 4 + mi][(qn) * 2 + ni] = __builtin_amdgcn_mfma_f32_16x16x32_bf16( \
          aR[mi][ks], bR[ni][ks], acc[(qm) * 4 + mi][(qn) * 2 + ni], 0, 0, 0); \
  } while (0)

#define PH_TAIL(qm, qn) do { \
    BAR(); LGKM0(); \
    __builtin_amdgcn_s_setprio(1); MMAQ(qm, qn); __builtin_amdgcn_s_setprio(0); \
    BAR(); } while (0)

// =================== 8-phase PV kernel (split-K=4) =============================
__global__ __launch_bounds__(512, 1) void pv8_kernel(
    const bf16* __restrict__ Sb, const bf16* __restrict__ vb,
    const float* __restrict__ rspart, Ptr8 slots) {
  unsigned nwg = gridDim.x;   // 256
  unsigned flat = blockIdx.x;
  unsigned swz = (flat & 7) * (nwg >> 3) + (flat >> 3);
  const unsigned zz = swz >> 5;
  const unsigned tile = swz & 31;
  const int m0 = (tile & 15) * 256;
  const int n0 = (tile >> 4) * 256;
  const int b = zz >> 2, s = zz & 3;
  const bf16* A = Sb + (size_t)b * 16777216 + s * 1024;
  const bf16* B = vb + (size_t)b * 2097152 + s * 1024;
  bf16* Cp = (bf16*)(slots.p[zz]);

  __shared__ bf16 lds[2][2][2][8192];
  __shared__ float rs_lds[256];

  const int t = threadIdx.x;
  const int l = t & 63;
  const int wid = t >> 6;
  const int wm = wid >> 2;
  const int wn = wid & 3;

  const int swzc = (((t & 7) ^ ((t >> 3) & 7)) << 3);
  const bf16* gA = A + (size_t)(m0 + (t >> 3)) * 4096 + swzc;
  const bf16* gB = B + (size_t)(n0 + (t >> 3)) * 4096 + swzc;

  f32x4 acc[8][4] = {};
  bf16x8 aR[4][2], bR[2][2];

  STG(0, 0, 0, 0, 4096);
  STG(0, 0, 1, 0, 4096);
  STG(1, 0, 0, 0, 4096);
  STG(1, 0, 1, 0, 4096);
  STG(1, 1, 0, 1, 4096);
  VMC0();
  BAR();

  #pragma unroll 1
  for (int j = 0; j < 7; j++) {
    const int kt1 = 2 * j + 1, kt2 = 2 * j + 2, kt3 = 2 * j + 3;
    DSA(0, 0); DSB(0, 0); STG(1, 1, 1, kt1, 4096); PH_TAIL(0, 0);
    DSA(0, 4);            STG(0, 1, 0, kt1, 4096); PH_TAIL(1, 0);
    DSB(0, 2);            STG(0, 1, 1, kt1, 4096); PH_TAIL(1, 1);
    DSA(0, 0);            STG(1, 0, 0, kt2, 4096); VMC2(); PH_TAIL(0, 1);
    DSA(1, 0); DSB(1, 0); STG(1, 0, 1, kt2, 4096); PH_TAIL(0, 0);
    DSA(1, 4);            STG(0, 0, 0, kt2, 4096); PH_TAIL(1, 0);
    DSB(1, 2);            STG(0, 0, 1, kt2, 4096); PH_TAIL(1, 1);
    DSA(1, 0);            STG(1, 1, 0, kt3, 4096); VMC2(); PH_TAIL(0, 1);
  }
  {
    const int kt1 = 15;
    DSA(0, 0); DSB(0, 0); STG(1, 1, 1, kt1, 4096); PH_TAIL(0, 0);
    DSA(0, 4);            STG(0, 1, 0, kt1, 4096); PH_TAIL(1, 0);
    DSB(0, 2);            STG(0, 1, 1, kt1, 4096); PH_TAIL(1, 1);
    DSA(0, 0);            VMC0(); PH_TAIL(0, 1);
    DSA(1, 0); DSB(1, 0); PH_TAIL(0, 0);
    DSA(1, 4);            PH_TAIL(1, 0);
    DSB(1, 2);            PH_TAIL(1, 1);
    DSA(1, 0);            PH_TAIL(0, 1);
  }

  if (t < 256) {
    const float4* pp = reinterpret_cast<const float4*>(
        rspart + (((size_t)b * 4096 + m0 + t) << 6));
    float ssum = 0.f;
    #pragma unroll
    for (int i2 = 0; i2 < 16; i2++) {
      float4 vv = pp[i2];
      ssum += vv.x + vv.y + vv.z + vv.w;
    }
    rs_lds[t] = 1.0f / ssum;
  }
  __syncthreads();

  #pragma unroll
  for (int mr = 0; mr < 8; mr++) {
    #pragma unroll
    for (int jj = 0; jj < 4; jj++) {
      int lrow = wm * 128 + mr * 16 + (l >> 4) * 4 + jj;
      float inv = rs_lds[lrow];
      int gm = m0 + lrow;
      #pragma unroll
      for (int nr = 0; nr < 4; nr++) {
        int gn = n0 + wn * 64 + nr * 16 + (l & 15);
        Cp[(size_t)gm * 512 + gn] = __float2bfloat16(acc[mr][nr][jj] * inv);
      }
    }
  }
}

// =================== 8-phase QK^T kernel: P = exp(scale*q.k) + rspart ==========
// M=N=4096, K=512 per batch; A = q rows (ld 1024), B = k rows (ld 1024).
__global__ __launch_bounds__(512, 1) void qk8_kernel(
    const bf16* __restrict__ qkb, bf16* __restrict__ Sb,
    float* __restrict__ rspart, float scale) {
  unsigned nwg = gridDim.x;   // 512
  unsigned flat = blockIdx.x;
  unsigned swz = (flat & 7) * (nwg >> 3) + (flat >> 3);
  const unsigned b = swz >> 8;
  const unsigned tile = swz & 255;       // 16 m-tiles x 16 n-tiles
  const int m0 = (tile & 15) * 256;
  const int n0 = (tile >> 4) * 256;
  const bf16* A = qkb + (size_t)b * 4194304;        // q: cols [0,512), ld 1024
  const bf16* B = qkb + (size_t)b * 4194304 + 512;  // k: cols [512,1024)
  bf16* Cp = Sb + (size_t)b * 16777216;

  __shared__ bf16 lds[2][2][2][8192];

  const int t = threadIdx.x;
  const int l = t & 63;
  const int wid = t >> 6;
  const int wm = wid >> 2;
  const int wn = wid & 3;

  const int swzc = (((t & 7) ^ ((t >> 3) & 7)) << 3);
  const bf16* gA = A + (size_t)(m0 + (t >> 3)) * 1024 + swzc;
  const bf16* gB = B + (size_t)(n0 + (t >> 3)) * 1024 + swzc;

  f32x4 acc[8][4] = {};
  bf16x8 aR[4][2], bR[2][2];

  // K=512 -> kt 0..7 (4 pairs): prologue + 3 full iters + tail
  STG(0, 0, 0, 0, 1024);
  STG(0, 0, 1, 0, 1024);
  STG(1, 0, 0, 0, 1024);
  STG(1, 0, 1, 0, 1024);
  STG(1, 1, 0, 1, 1024);
  VMC0();
  BAR();

  #pragma unroll 1
  for (int j = 0; j < 3; j++) {
    const int kt1 = 2 * j + 1, kt2 = 2 * j + 2, kt3 = 2 * j + 3;
    DSA(0, 0); DSB(0, 0); STG(1, 1, 1, kt1, 1024); PH_TAIL(0, 0);
    DSA(0, 4);            STG(0, 1, 0, kt1, 1024); PH_TAIL(1, 0);
    DSB(0, 2);            STG(0, 1, 1, kt1, 1024); PH_TAIL(1, 1);
    DSA(0, 0);            STG(1, 0, 0, kt2, 1024); VMC2(); PH_TAIL(0, 1);
    DSA(1, 0); DSB(1, 0); STG(1, 0, 1, kt2, 1024); PH_TAIL(0, 0);
    DSA(1, 4);            STG(0, 0, 0, kt2, 1024); PH_TAIL(1, 0);
    DSB(1, 2);            STG(0, 0, 1, kt2, 1024); PH_TAIL(1, 1);
    DSA(1, 0);            STG(1, 1, 0, kt3, 1024); VMC2(); PH_TAIL(0, 1);
  }
  {
    const int kt1 = 7;
    DSA(0, 0); DSB(0, 0); STG(1, 1, 1, kt1, 1024); PH_TAIL(0, 0);
    DSA(0, 4);            STG(0, 1, 0, kt1, 1024); PH_TAIL(1, 0);
    DSB(0, 2);            STG(0, 1, 1, kt1, 1024); PH_TAIL(1, 1);
    DSA(0, 0);            VMC0(); PH_TAIL(0, 1);
    DSA(1, 0); DSB(1, 0); PH_TAIL(0, 0);
    DSA(1, 4);            PH_TAIL(1, 0);
    DSB(1, 2);            PH_TAIL(1, 1);
    DSA(1, 0);            PH_TAIL(0, 1);
  }

  // epilogue: e = exp(acc*scale); store bf16 P; per-row partial sums -> rspart
  const int ntile = tile >> 4;   // n-block index 0..15; slot = ntile*4 + wn
  #pragma unroll
  for (int mr = 0; mr < 8; mr++) {
    #pragma unroll
    for (int jj = 0; jj < 4; jj++) {
      int gm = m0 + wm * 128 + mr * 16 + (l >> 4) * 4 + jj;
      float rsum = 0.f;
      #pragma unroll
      for (int nr = 0; nr < 4; nr++) {
        int gn = n0 + wn * 64 + nr * 16 + (l & 15);
        float e = __expf(acc[mr][nr][jj] * scale);
        rsum += e;
        Cp[(size_t)gm * 4096 + gn] = __float2bfloat16(e);
      }
      rsum += __shfl_xor(rsum, 1);
      rsum += __shfl_xor(rsum, 2);
      rsum += __shfl_xor(rsum, 4);
      rsum += __shfl_xor(rsum, 8);
      if ((l & 15) == 0)
        rspart[(((size_t)b * 4096 + gm) << 6) + ntile * 4 + wn] = rsum;
    }
  }
}

// ---------------- PV split-K fallback (small-ws path), 128^2 structure ---------
__global__ __launch_bounds__(256, 4) void pv_split_kernel(
    const bf16* __restrict__ Sb, const bf16* __restrict__ vb,
    const float* __restrict__ rspart,
    long long sS, long long sV, Ptr8 slots, int mode) {
  unsigned nx = gridDim.x, ny = gridDim.y;
  unsigned flat = (blockIdx.z * ny + blockIdx.y) * nx + blockIdx.x;
  unsigned nwg = nx * ny * gridDim.z;
  unsigned swz = (flat & 7) * (nwg >> 3) + (flat >> 3);
  unsigned bxi = swz % nx;
  unsigned tmp = swz / nx;
  unsigned byi = tmp % ny;
  unsigned bz  = tmp / ny;

  const int z = bz;
  const int b = mode ? 0 : (z >> 2);
  const int s = mode ? z : (z & 3);
  const bf16* A = Sb + (size_t)b * sS + s * 1024;
  const bf16* B = vb + (size_t)b * sV + s * 1024;
  bf16* Cp = (bf16*)(slots.p[z]);
  const int m0 = bxi * 128, n0 = byi * 128;

  __shared__ bf16 ldsA[128 * 64];
  __shared__ bf16 ldsB[128 * 64];
  __shared__ float rs_lds[128];

  const int t = threadIdx.x;

  if (t < 128) {
    const float4* pp = reinterpret_cast<const float4*>(rspart + (((size_t)b * 4096 + m0 + t) << 6));
    float ssum = 0.f;
    #pragma unroll
    for (int i2 = 0; i2 < 16; i2++) {
      float4 vv = pp[i2];
      ssum += vv.x + vv.y + vv.z + vv.w;
    }
    rs_lds[t] = 1.0f / ssum;
  }

  const int lane = t & 63, wv = t >> 6;
  const int wr = (wv >> 1) * 64, wc = (wv & 1) * 64;

  const int r0 = t >> 3;
  const int cb = ((t & 7) << 4) ^ ((r0 & 7) << 4);
  const bf16* gA = A + (size_t)(m0 + r0) * 4096 + (cb >> 1);
  const bf16* gB = B + (size_t)(n0 + r0) * 4096 + (cb >> 1);
  bf16* lA = ldsA + t * 8;
  bf16* lB = ldsB + t * 8;

  const int arow = wr + (lane & 15);
  const int brow = wc + (lane & 15);
  const int kb   = (lane >> 4) * 16;

  f32x4 acc[4][4] = {};

  for (int k0 = 0; k0 < 1024; k0 += 64) {
    #pragma unroll
    for (int i = 0; i < 4; i++) {
      async16(gA + (size_t)i * 32 * 4096 + k0, lA + i * 2048);
      async16(gB + (size_t)i * 32 * 4096 + k0, lB + i * 2048);
    }
    __syncthreads();
    #pragma unroll
    for (int ks = 0; ks < 2; ks++) {
      bf16x8 af[4], bfr[4];
      #pragma unroll
      for (int f = 0; f < 4; f++) {
        int ra = arow + f * 16;
        af[f] = *reinterpret_cast<const bf16x8*>(
            reinterpret_cast<const char*>(ldsA) + ra * 128 + ((ks * 64 + kb) ^ ((ra & 7) << 4)));
        int rb = brow + f * 16;
        bfr[f] = *reinterpret_cast<const bf16x8*>(
            reinterpret_cast<const char*>(ldsB) + rb * 128 + ((ks * 64 + kb) ^ ((rb & 7) << 4)));
      }
      #pragma unroll
      for (int fm = 0; fm < 4; fm++)
        #pragma unroll
        for (int fn = 0; fn < 4; fn++)
          acc[fm][fn] = __builtin_amdgcn_mfma_f32_16x16x32_bf16(af[fm], bfr[fn], acc[fm][fn], 0, 0, 0);
    }
    __syncthreads();
  }

  #pragma unroll
  for (int fm = 0; fm < 4; fm++) {
    #pragma unroll
    for (int j = 0; j < 4; j++) {
      int lrow = wr + fm * 16 + (lane >> 4) * 4 + j;
      float inv = rs_lds[lrow];
      int gm = m0 + lrow;
      #pragma unroll
      for (int fn = 0; fn < 4; fn++) {
        int gn = n0 + wc + fn * 16 + (lane & 15);
        Cp[(size_t)gm * 512 + gn] = __float2bfloat16(acc[fm][fn][j] * inv);
      }
    }
  }
}

// ---------------- merged split-K reduce (both batches, one launch) -------------
__global__ __launch_bounds__(256) void reduce3x2_kernel(bf16* __restrict__ o,
    const bf16* __restrict__ h, const bf16* __restrict__ qk) {
  int i = (blockIdx.x * 256 + threadIdx.x) * 8;
  int b = i >> 21;
  int ii = i & 2097151;
  bf16* dst = o + (size_t)b * 2097152 + ii;
  const bf16* p1 = h + (size_t)b * 2097152 + ii;
  const bf16* p2 = qk + (size_t)b * 2 * 2097152 + ii;
  const bf16* p3 = qk + (size_t)(b * 2 + 1) * 2097152 + ii;
  bf16x8 a  = *reinterpret_cast<const bf16x8*>(dst);
  bf16x8 v1 = *reinterpret_cast<const bf16x8*>(p1);
  bf16x8 v2 = *reinterpret_cast<const bf16x8*>(p2);
  bf16x8 v3 = *reinterpret_cast<const bf16x8*>(p3);
  bf16x8 r;
  #pragma unroll
  for (int j = 0; j < 8; j++)
    r[j] = f2bfb(bfb2f(a[j]) + bfb2f(v1[j]) + bfb2f(v2[j]) + bfb2f(v3[j]));
  *reinterpret_cast<bf16x8*>(dst) = r;
}

// ---------------- fallback reduce --------------------------------------------
__global__ __launch_bounds__(256) void reduce3_kernel(bf16* __restrict__ dst,
    const bf16* __restrict__ p1, const bf16* __restrict__ p2,
    const bf16* __restrict__ p3) {
  int i = (blockIdx.x * 256 + threadIdx.x) * 8;
  bf16x8 a  = *reinterpret_cast<const bf16x8*>(dst + i);
  bf16x8 v1 = *reinterpret_cast<const bf16x8*>(p1 + i);
  bf16x8 v2 = *reinterpret_cast<const bf16x8*>(p2 + i);
  bf16x8 v3 = *reinterpret_cast<const bf16x8*>(p3 + i);
  bf16x8 r;
  #pragma unroll
  for (int j = 0; j < 8; j++)
    r[j] = f2bfb(bfb2f(a[j]) + bfb2f(v1[j]) + bfb2f(v2[j]) + bfb2f(v3[j]));
  *reinterpret_cast<bf16x8*>(dst + i) = r;
}

extern "C" void kernel_launch(void* const* d_in, const int* in_sizes, int n_in,
                              void* d_out, int out_size, void* d_ws, size_t ws_size,
                              hipStream_t stream) {
  const float* x     = (const float*)d_in[0];
  const float* gamma = (const float*)d_in[1];
  const float* beta  = (const float*)d_in[2];
  const float* wq    = (const float*)d_in[3];
  const float* bq    = (const float*)d_in[4];
  const float* wk    = (const float*)d_in[5];
  const float* bk    = (const float*)d_in[6];
  const float* wv    = (const float*)d_in[7];
  const float* bv    = (const float*)d_in[8];
  const float* wp    = (const float*)d_in[9];
  const float* bp    = (const float*)d_in[10];
  float* out = (float*)d_out;

  char* w = (char*)d_ws;
  size_t off = 0;
  float* pstats = (float*)(w + off);   off += 4096;
  float* bqk    = (float*)(w + off);   off += 4096;
  float* rspart = (float*)(w + off);   off += (size_t)2 * 4096 * 64 * 4;
  bf16* wqkb = (bf16*)(w + off);       off += (size_t)1024 * 512 * 2;
  bf16* wvb  = (bf16*)(w + off);       off += (size_t)512 * 512 * 2;
  bf16* wpb  = (bf16*)(w + off);       off += (size_t)512 * 512 * 2;
  bf16* h    = (bf16*)(w + off);       off += (size_t)2 * NPX * CCH * 2;
  bf16* qk   = (bf16*)(w + off);       off += (size_t)2 * NPX * 1024 * 2;
  bf16* v    = (bf16*)(w + off);       off += (size_t)2 * NPX * CCH * 2;
  bf16* o    = (bf16*)(w + off);       off += (size_t)2 * NPX * CCH * 2;
  bf16* S    = (bf16*)(w + off);
  size_t need_big = off + (size_t)2 * NPX * NPX * 2;
  const bool big = ws_size >= need_big;

  const long long sBN = (long long)NPX * CCH;
  const long long sQK = (long long)NPX * 1024;
  const long long sS  = (long long)NPX * NPX;
  const float scale = 0.04419417382415922f;

  prep_kernel<<<1536, 256, 0, stream>>>(wq, wk, wv, wp, bq, bk, x, wqkb, bqk, pstats);
  gn_apply_kernel<<<dim3(8, 64, 2), 256, 0, stream>>>(x, pstats, gamma, beta, h);

  GemmP pqkv = {h, wqkb, qk, nullptr, bqk, nullptr, nullptr,
                1.f, 512, 512, 512, 1024, sBN, 0, sQK, 0, 32, 8, 1};
  GemmP pv   = {wvb, h, v, bv, nullptr, nullptr, nullptr,
                1.f, 512, 512, 512, 4096, 0, sBN, sBN, 0, 4, 32, 1};
  gemm_any_kernel<<<768, 256, 0, stream>>>(pqkv, pv, 512);

  if (big) {
    qk8_kernel<<<512, 512, 0, stream>>>(qk, S, rspart, scale);
    Ptr8 slots{{o, h, qk, qk + sBN, o + sBN, h + sBN, qk + 2 * sBN, qk + 3 * sBN}};
    pv8_kernel<<<256, 512, 0, stream>>>(S, v, rspart, slots);
    reduce3x2_kernel<<<2048, 256, 0, stream>>>(o, h, qk);
  } else {
    for (int b = 0; b < 2; b++) {
      GemmP ps = {qk + b * sQK, qk + b * sQK + 512, S, nullptr, nullptr, nullptr,
                  rspart + ((size_t)b << 18),
                  scale, 512, 1024, 1024, 4096, 0, 0, 0, 0, 32, 32, 2};
      gemm_any_kernel<<<1024, 256, 0, stream>>>(ps, ps, 1024);
      Ptr8 slots{{o + b * sBN, h, h + sBN, (bf16*)out, nullptr, nullptr, nullptr, nullptr}};
      pv_split_kernel<<<dim3(32, 4, 4), 256, 0, stream>>>(S, v + b * sBN,
          rspart + ((size_t)b << 18), 0, 0, slots, 1);
      reduce3_kernel<<<1024, 256, 0, stream>>>(o + b * sBN, h, h + sBN, (bf16*)out);
    }
  }

  GemmP po = {wpb, o, out, bp, nullptr, x, nullptr,
              1.f, 512, 512, 512, 4096, 0, sBN, sBN, sBN, 4, 32, 0};
  gemm_any_kernel<<<256, 256, 0, stream>>>(po, po, 256);
}